// Round 1
// baseline (826.589 us; speedup 1.0000x reference)
//
#include <hip/hip_runtime.h>

// ---- problem constants ----
#define KW 11
#define NB 2            // N * C
#define DI 96
#define HI 256
#define WI 256
#define DOUT 86
#define HOUT 246
#define WOUT 246
#define HT 16           // output tile height
#define WT 16           // output tile width
#define TH 16           // ceil(246/16)
#define TW 16
#define DCH 2           // chunks along D
#define DPC 43          // output d per chunk (86 = 2*43)
#define ZS (DPC + KW - 1)   // 53 input slices per chunk
#define RR (HT + KW - 1)    // 26 region rows
#define RC (WT + KW - 1)    // 26 region cols
#define RST 28              // padded row stride (16B-aligned rows)
#define SSIM_C1 1e-4f
#define SSIM_C2 9e-4f
#define NBLK (TH * TW * NB * DCH)   // 1024

static __global__ __launch_bounds__(256, 4) void ssim_main(
    const float* __restrict__ img1, const float* __restrict__ img2,
    const float* __restrict__ win, float* __restrict__ bsum)
{
    __shared__ __align__(16) float raw[2][RR][RST];   // raw img tiles (W halo)
    __shared__ __align__(16) float4 A4[RR][WT];       // W-conv out: s1,s2,s11,s22
    __shared__ float  A1[RR][WT];                     // W-conv out: s12
    __shared__ float  w1s[KW];
    __shared__ float  red[4];

    const int t = threadIdx.x;
    const int tw_ = blockIdx.x, th_ = blockIdx.y;
    const int bz = blockIdx.z;            // 0..3 : n*2 + chunk
    const int n = bz >> 1, chunk = bz & 1;
    const int d0 = chunk * DPC;
    const int h0 = th_ * HT, w0 = tw_ * WT;

    // 1-D separable profile from marginal sums of the 3-D window (exact for
    // a normalized separable window, which this gaussian is).
    if (t < KW) {
        float s = 0.f;
        const float* wp = win + t * (KW * KW);
        for (int m = 0; m < KW * KW; ++m) s += wp[m];
        w1s[t] = s;
    }
    __syncthreads();
    float w1r[KW];
    #pragma unroll
    for (int k = 0; k < KW; ++k) w1r[k] = w1s[k];

    // D-conv shift-register: acc[p] accumulates output slice d = zz - p.
    float a1[KW], a2[KW], a11[KW], a22[KW], a12[KW];
    #pragma unroll
    for (int p = 0; p < KW; ++p) { a1[p]=0.f; a2[p]=0.f; a11[p]=0.f; a22[p]=0.f; a12[p]=0.f; }

    const int ty = t >> 4, tx = t & 15;
    const int oh = h0 + ty, ow = w0 + tx;
    const bool valid = (oh < HOUT) && (ow < WOUT);
    float partial = 0.f;

    for (int zz = 0; zz < ZS; ++zz) {
        const int z = d0 + zz;

        __syncthreads();   // A readers (prev stepB) done before stepA rewrites; raw readers done
        // ---- stage raw tile (both images), zero-pad OOB ----
        for (int u = t; u < 2 * RR * RC; u += 256) {
            const int im = (u >= RR * RC) ? 1 : 0;
            const int pos = u - im * (RR * RC);
            const int r = pos / RC, c = pos - r * RC;
            const int gh = h0 + r, gw = w0 + c;
            float v = 0.f;
            if (gh < HI && gw < WI)
                v = (im ? img2 : img1)[((n * DI + z) * HI + gh) * WI + gw];
            raw[im][r][c] = v;
        }
        __syncthreads();

        // ---- step A: W-conv of the 5 fields (on-the-fly products) ----
        // 26 rows x 4 col-groups, 4 outputs per task, float4 LDS reads.
        if (t < RR * 4) {
            const int r = t >> 2, g = t & 3;
            const int c0 = g * 4;
            float wa[16], wb[16];
            #pragma unroll
            for (int m = 0; m < 4; ++m) {
                float4 va = *(const float4*)&raw[0][r][c0 + 4 * m];
                float4 vb = *(const float4*)&raw[1][r][c0 + 4 * m];
                wa[4*m+0]=va.x; wa[4*m+1]=va.y; wa[4*m+2]=va.z; wa[4*m+3]=va.w;
                wb[4*m+0]=vb.x; wb[4*m+1]=vb.y; wb[4*m+2]=vb.z; wb[4*m+3]=vb.w;
            }
            float s1[4], s2[4], s11[4], s22[4], s12[4];
            #pragma unroll
            for (int o = 0; o < 4; ++o) { s1[o]=0.f; s2[o]=0.f; s11[o]=0.f; s22[o]=0.f; s12[o]=0.f; }
            #pragma unroll
            for (int k = 0; k < KW; ++k) {
                const float wk = w1r[k];
                #pragma unroll
                for (int o = 0; o < 4; ++o) {
                    const float x = wa[o + k], y = wb[o + k];
                    const float px = wk * x, py = wk * y;
                    s1[o] += px; s2[o] += py;
                    s11[o] = fmaf(px, x, s11[o]);
                    s22[o] = fmaf(py, y, s22[o]);
                    s12[o] = fmaf(px, y, s12[o]);
                }
            }
            #pragma unroll
            for (int o = 0; o < 4; ++o) {
                A4[r][c0 + o] = make_float4(s1[o], s2[o], s11[o], s22[o]);
                A1[r][c0 + o] = s12[o];
            }
        }
        __syncthreads();

        // ---- step B: H-conv -> per-thread WH value; feed D shift-register ----
        float f1=0.f, f2=0.f, f11=0.f, f22=0.f, f12=0.f;
        #pragma unroll
        for (int kh = 0; kh < KW; ++kh) {
            const float w = w1r[kh];
            const float4 v = A4[ty + kh][tx];
            const float u = A1[ty + kh][tx];
            f1  = fmaf(w, v.x, f1);
            f2  = fmaf(w, v.y, f2);
            f11 = fmaf(w, v.z, f11);
            f22 = fmaf(w, v.w, f22);
            f12 = fmaf(w, u, f12);
        }
        #pragma unroll
        for (int p = 0; p < KW; ++p) {
            const float w = w1r[p];
            a1[p]  = fmaf(w, f1,  a1[p]);
            a2[p]  = fmaf(w, f2,  a2[p]);
            a11[p] = fmaf(w, f11, a11[p]);
            a22[p] = fmaf(w, f22, a22[p]);
            a12[p] = fmaf(w, f12, a12[p]);
        }

        if (zz >= KW - 1) {   // output slice d = zz-10 complete
            const float mu1 = a1[KW-1], mu2 = a2[KW-1];
            const float e11 = a11[KW-1], e22 = a22[KW-1], e12 = a12[KW-1];
            const float m11 = mu1 * mu1, m22 = mu2 * mu2, m12 = mu1 * mu2;
            const float num = (2.f * m12 + SSIM_C1) * (2.f * (e12 - m12) + SSIM_C2);
            const float den = (m11 + m22 + SSIM_C1) * ((e11 - m11) + (e22 - m22) + SSIM_C2);
            if (valid) partial += num / den;
        }
        #pragma unroll
        for (int p = KW - 1; p >= 1; --p) {
            a1[p]=a1[p-1]; a2[p]=a2[p-1]; a11[p]=a11[p-1]; a22[p]=a22[p-1]; a12[p]=a12[p-1];
        }
        a1[0]=0.f; a2[0]=0.f; a11[0]=0.f; a22[0]=0.f; a12[0]=0.f;
    }

    // ---- block reduction -> per-block partial sum ----
    #pragma unroll
    for (int off = 32; off >= 1; off >>= 1)
        partial += __shfl_down(partial, off, 64);
    if ((t & 63) == 0) red[t >> 6] = partial;
    __syncthreads();
    if (t == 0) {
        bsum[(blockIdx.z * gridDim.y + blockIdx.y) * gridDim.x + blockIdx.x]
            = red[0] + red[1] + red[2] + red[3];
    }
}

static __global__ __launch_bounds__(256) void ssim_reduce(
    const float* __restrict__ bsum, float* __restrict__ out)
{
    __shared__ double red[4];
    const int t = threadIdx.x;
    double s = 0.0;
    for (int i = t; i < NBLK; i += 256) s += (double)bsum[i];
    #pragma unroll
    for (int off = 32; off >= 1; off >>= 1)
        s += __shfl_down(s, off, 64);
    if ((t & 63) == 0) red[t >> 6] = s;
    __syncthreads();
    if (t == 0) {
        const double tot = red[0] + red[1] + red[2] + red[3];
        out[0] = (float)(tot / (double)((long)NB * DOUT * HOUT * WOUT));
    }
}

extern "C" void kernel_launch(void* const* d_in, const int* in_sizes, int n_in,
                              void* d_out, int out_size, void* d_ws, size_t ws_size,
                              hipStream_t stream)
{
    const float* img1 = (const float*)d_in[0];
    const float* img2 = (const float*)d_in[1];
    const float* win  = (const float*)d_in[2];
    float* out  = (float*)d_out;
    float* bsum = (float*)d_ws;   // 1024 floats = 4 KB scratch

    dim3 grid(TW, TH, NB * DCH);
    ssim_main<<<grid, 256, 0, stream>>>(img1, img2, win, bsum);
    ssim_reduce<<<1, 256, 0, stream>>>(bsum, out);
}

// Round 2
// 222.217 us; speedup vs baseline: 3.7197x; 3.7197x over previous
//
#include <hip/hip_runtime.h>

// ---- problem constants ----
#define KW 11
#define NB 2            // N * C
#define DI 96
#define HI 256
#define WI 256
#define DOUT 86
#define HOUT 246
#define WOUT 246
#define HT 16           // output tile height
#define WT 16           // output tile width
#define TH 16           // ceil(246/16)
#define TW 16
#define DCH 2           // chunks along D
#define DPC 43          // output d per chunk (86 = 2*43)
#define ZS (DPC + KW - 1)   // 53 input slices per chunk
#define RR (HT + KW - 1)    // 26 region rows
#define RST 28              // staged cols (7 x float4, 16B-aligned rows)
#define SSIM_C1 1e-4f
#define SSIM_C2 9e-4f
#define NBLK (TH * TW * NB * DCH)   // 1024

// Ring-buffer D-conv step with compile-time slot indices (no reg moves,
// no dynamic indexing -> everything stays in VGPRs).
template<int J>
__device__ __forceinline__ void acc_step(
    float (&A)[KW], float (&B)[KW], float (&P)[KW], float (&Q)[KW],
    const float (&w)[KW], float f1, float f2, float f3, float f4,
    bool emit, float& o1, float& o2, float& o3, float& o4)
{
    #pragma unroll
    for (int p = 0; p < KW; ++p) {
        const int s = (J - p + KW) % KW;   // compile-time
        A[s] = fmaf(w[p], f1, A[s]);
        B[s] = fmaf(w[p], f2, B[s]);
        P[s] = fmaf(w[p], f3, P[s]);
        Q[s] = fmaf(w[p], f4, Q[s]);
    }
    const int C = (J + 1) % KW;            // completed slot (d = zz-10)
    if (emit) { o1 = A[C]; o2 = B[C]; o3 = P[C]; o4 = Q[C]; }
    A[C] = 0.f; B[C] = 0.f; P[C] = 0.f; Q[C] = 0.f;
}

static __global__ __launch_bounds__(256, 2) void ssim_main(
    const float* __restrict__ img1, const float* __restrict__ img2,
    const float* __restrict__ win, float* __restrict__ bsum)
{
    __shared__ __align__(16) float raw[2][RR][RST];     // raw tiles, 5.8 KB
    __shared__ __align__(16) float4 A4[RR][WT + 1];     // W-conv out (padded stride)
    __shared__ float w1s[KW];
    __shared__ float tmpw[121];
    __shared__ float red[4];

    const int t = threadIdx.x;
    const int tw_ = blockIdx.x, th_ = blockIdx.y;
    const int bz = blockIdx.z;            // 0..3 : n*2 + chunk
    const int n = bz >> 1, chunk = bz & 1;
    const int d0 = chunk * DPC;
    const int h0 = th_ * HT, w0 = tw_ * WT;

    // 1-D separable profile from marginal sums of the 3-D window.
    if (t < 121) {
        const int i = t / KW, j = t - i * KW;
        const float* wp = win + i * (KW * KW) + j * KW;
        float s = 0.f;
        #pragma unroll
        for (int m = 0; m < KW; ++m) s += wp[m];
        tmpw[t] = s;
    }
    __syncthreads();
    if (t < KW) {
        float s = 0.f;
        #pragma unroll
        for (int j = 0; j < KW; ++j) s += tmpw[t * KW + j];
        w1s[t] = s;
    }
    __syncthreads();
    float w1r[KW];
    #pragma unroll
    for (int k = 0; k < KW; ++k) w1r[k] = w1s[k];

    // D-conv ring accumulators: 4 fields (a, b, ab, a^2+b^2).
    float rA[KW], rB[KW], rP[KW], rQ[KW];
    #pragma unroll
    for (int p = 0; p < KW; ++p) { rA[p]=0.f; rB[p]=0.f; rP[p]=0.f; rQ[p]=0.f; }

    const int ty = t >> 4, tx = t & 15;
    const bool valid = (h0 + ty < HOUT) && (w0 + tx < WOUT);
    float partial = 0.f;

    const long ibase = (long)n * DI * HI * WI;
    int jj = 0;   // zz % 11, maintained incrementally (uniform scalar)

    for (int zz = 0; zz < ZS; ++zz) {
        const int z = d0 + zz;
        const long sbase = ibase + (long)z * HI * WI;

        __syncthreads();   // prev step A raw-readers & prev step B A4-readers done
        // ---- stage raw tile (both images) as float4 rows, zero-pad OOB ----
        for (int u = t; u < 2 * RR * 7; u += 256) {
            const int im = (u >= RR * 7) ? 1 : 0;
            const int pos = u - im * (RR * 7);
            const int r = pos / 7, c4 = pos - r * 7;
            const int gh = h0 + r, gw0 = w0 + 4 * c4;
            float4 v = make_float4(0.f, 0.f, 0.f, 0.f);
            if (gh < HI) {
                const float* src = (im ? img2 : img1) + sbase + (long)gh * WI + gw0;
                if (gw0 + 3 < WI) v = *(const float4*)src;
                else {
                    if (gw0     < WI) v.x = src[0];
                    if (gw0 + 1 < WI) v.y = src[1];
                    if (gw0 + 2 < WI) v.z = src[2];
                }
            }
            *(float4*)&raw[im][r][4 * c4] = v;
        }
        __syncthreads();

        // ---- step A: W-conv of 4 fields, 208 threads x 2 outputs ----
        if (t < RR * 8) {
            const int r = t >> 3, c0 = (t & 7) * 2;
            float xa[12], xb[12];
            #pragma unroll
            for (int m = 0; m < 6; ++m) {
                const float2 va = *(const float2*)&raw[0][r][c0 + 2 * m];
                const float2 vb = *(const float2*)&raw[1][r][c0 + 2 * m];
                xa[2*m] = va.x; xa[2*m+1] = va.y;
                xb[2*m] = vb.x; xb[2*m+1] = vb.y;
            }
            float s1[2] = {0.f, 0.f}, s2[2] = {0.f, 0.f};
            float s3[2] = {0.f, 0.f}, s4[2] = {0.f, 0.f};
            #pragma unroll
            for (int k = 0; k < KW; ++k) {
                const float wk = w1r[k];
                #pragma unroll
                for (int o = 0; o < 2; ++o) {
                    const float x = xa[o + k], y = xb[o + k];
                    s1[o] = fmaf(wk, x, s1[o]);
                    s2[o] = fmaf(wk, y, s2[o]);
                    s3[o] = fmaf(wk, x * y, s3[o]);
                    s4[o] = fmaf(wk, fmaf(x, x, y * y), s4[o]);
                }
            }
            #pragma unroll
            for (int o = 0; o < 2; ++o)
                A4[r][c0 + o] = make_float4(s1[o], s2[o], s3[o], s4[o]);
        }
        __syncthreads();

        // ---- step B: H-conv -> per-thread value; feed D ring ----
        float f1 = 0.f, f2 = 0.f, f3 = 0.f, f4 = 0.f;
        #pragma unroll
        for (int kh = 0; kh < KW; ++kh) {
            const float w = w1r[kh];
            const float4 v = A4[ty + kh][tx];
            f1 = fmaf(w, v.x, f1);
            f2 = fmaf(w, v.y, f2);
            f3 = fmaf(w, v.z, f3);
            f4 = fmaf(w, v.w, f4);
        }

        const bool emit = (zz >= KW - 1);
        float o1, o2, o3, o4;
        switch (jj) {
            case 0:  acc_step<0>(rA,rB,rP,rQ,w1r,f1,f2,f3,f4,emit,o1,o2,o3,o4); break;
            case 1:  acc_step<1>(rA,rB,rP,rQ,w1r,f1,f2,f3,f4,emit,o1,o2,o3,o4); break;
            case 2:  acc_step<2>(rA,rB,rP,rQ,w1r,f1,f2,f3,f4,emit,o1,o2,o3,o4); break;
            case 3:  acc_step<3>(rA,rB,rP,rQ,w1r,f1,f2,f3,f4,emit,o1,o2,o3,o4); break;
            case 4:  acc_step<4>(rA,rB,rP,rQ,w1r,f1,f2,f3,f4,emit,o1,o2,o3,o4); break;
            case 5:  acc_step<5>(rA,rB,rP,rQ,w1r,f1,f2,f3,f4,emit,o1,o2,o3,o4); break;
            case 6:  acc_step<6>(rA,rB,rP,rQ,w1r,f1,f2,f3,f4,emit,o1,o2,o3,o4); break;
            case 7:  acc_step<7>(rA,rB,rP,rQ,w1r,f1,f2,f3,f4,emit,o1,o2,o3,o4); break;
            case 8:  acc_step<8>(rA,rB,rP,rQ,w1r,f1,f2,f3,f4,emit,o1,o2,o3,o4); break;
            case 9:  acc_step<9>(rA,rB,rP,rQ,w1r,f1,f2,f3,f4,emit,o1,o2,o3,o4); break;
            default: acc_step<10>(rA,rB,rP,rQ,w1r,f1,f2,f3,f4,emit,o1,o2,o3,o4); break;
        }
        jj = (jj == KW - 1) ? 0 : jj + 1;

        if (emit && valid) {
            const float mu1 = o1, mu2 = o2;
            const float m11 = mu1 * mu1, m22 = mu2 * mu2, m12 = mu1 * mu2;
            const float sig12x2 = 2.f * (o3 - m12);
            const float sigsum  = o4 - m11 - m22;
            const float num = (2.f * m12 + SSIM_C1) * (sig12x2 + SSIM_C2);
            const float den = (m11 + m22 + SSIM_C1) * (sigsum + SSIM_C2);
            partial += num / den;
        }
    }

    // ---- block reduction -> per-block partial sum ----
    #pragma unroll
    for (int off = 32; off >= 1; off >>= 1)
        partial += __shfl_down(partial, off, 64);
    if ((t & 63) == 0) red[t >> 6] = partial;
    __syncthreads();
    if (t == 0) {
        bsum[(blockIdx.z * gridDim.y + blockIdx.y) * gridDim.x + blockIdx.x]
            = red[0] + red[1] + red[2] + red[3];
    }
}

static __global__ __launch_bounds__(256) void ssim_reduce(
    const float* __restrict__ bsum, float* __restrict__ out)
{
    __shared__ double red[4];
    const int t = threadIdx.x;
    double s = 0.0;
    for (int i = t; i < NBLK; i += 256) s += (double)bsum[i];
    #pragma unroll
    for (int off = 32; off >= 1; off >>= 1)
        s += __shfl_down(s, off, 64);
    if ((t & 63) == 0) red[t >> 6] = s;
    __syncthreads();
    if (t == 0) {
        const double tot = red[0] + red[1] + red[2] + red[3];
        out[0] = (float)(tot / (double)((long)NB * DOUT * HOUT * WOUT));
    }
}

extern "C" void kernel_launch(void* const* d_in, const int* in_sizes, int n_in,
                              void* d_out, int out_size, void* d_ws, size_t ws_size,
                              hipStream_t stream)
{
    const float* img1 = (const float*)d_in[0];
    const float* img2 = (const float*)d_in[1];
    const float* win  = (const float*)d_in[2];
    float* out  = (float*)d_out;
    float* bsum = (float*)d_ws;   // 1024 floats = 4 KB scratch

    dim3 grid(TW, TH, NB * DCH);
    ssim_main<<<grid, 256, 0, stream>>>(img1, img2, win, bsum);
    ssim_reduce<<<1, 256, 0, stream>>>(bsum, out);
}

// Round 3
// 206.299 us; speedup vs baseline: 4.0068x; 1.0772x over previous
//
#include <hip/hip_runtime.h>

// ---- problem constants ----
#define KW 11
#define NB 2            // N * C
#define DI 96
#define HI 256
#define WI 256
#define DOUT 86
#define HOUT 246
#define WOUT 246
#define HT 16           // output tile height
#define WT 16           // output tile width
#define TH 16
#define TW 16
#define DCH 4           // chunks along D
#define DPC 22          // output d per chunk (4*22 = 88 >= 86, last chunk 20)
#define RR (HT + KW - 1)    // 26 region rows
#define RST 28              // staged row stride in floats (16B-aligned)
#define HSZ (HI * WI)
#define SSIM_C1 1e-4f
#define SSIM_C2 9e-4f
#define NBLK (TH * TW * NB * DCH)   // 2048
#define NTASK (2 * RR * 7)          // 364 staging tasks (2 img x 26 rows x 7 float4)

// Ring-buffer D-conv step with compile-time slot indices.
template<int J>
__device__ __forceinline__ void acc_step(
    float (&A)[KW], float (&B)[KW], float (&P)[KW], float (&Q)[KW],
    const float (&w)[KW], float f1, float f2, float f3, float f4,
    bool emit, float& o1, float& o2, float& o3, float& o4)
{
    #pragma unroll
    for (int p = 0; p < KW; ++p) {
        const int s = (J - p + KW) % KW;   // compile-time
        A[s] = fmaf(w[p], f1, A[s]);
        B[s] = fmaf(w[p], f2, B[s]);
        P[s] = fmaf(w[p], f3, P[s]);
        Q[s] = fmaf(w[p], f4, Q[s]);
    }
    const int C = (J + 1) % KW;            // completed slot (d = zz-10)
    if (emit) { o1 = A[C]; o2 = B[C]; o3 = P[C]; o4 = Q[C]; }
    A[C] = 0.f; B[C] = 0.f; P[C] = 0.f; Q[C] = 0.f;
}

static __global__ __launch_bounds__(256, 2) void ssim_main(
    const float* __restrict__ img1, const float* __restrict__ img2,
    const float* __restrict__ win, float* __restrict__ bsum)
{
    __shared__ __align__(16) float rawf[2 * RR * RST];   // raw tiles, 5.8 KB
    __shared__ __align__(16) float4 A4[RR][WT + 1];      // W-conv out (padded)
    __shared__ float w1s[KW];
    __shared__ float tmpw[121];
    __shared__ float red[4];

    const int t = threadIdx.x;
    const int bz = blockIdx.z;            // 0..7 : n*4 + chunk
    const int n = bz >> 2, chunk = bz & 3;
    const int d0 = chunk * DPC;
    const int dpc = (DOUT - d0 < DPC) ? (DOUT - d0) : DPC;   // 22,22,22,20
    const int ZSL = dpc + KW - 1;                             // 32 or 30
    const int h0 = blockIdx.y * HT, w0 = blockIdx.x * WT;

    // 1-D separable profile from marginal sums of the 3-D window.
    if (t < 121) {
        const int i = t / KW, j = t - i * KW;
        const float* wp = win + i * (KW * KW) + j * KW;
        float s = 0.f;
        #pragma unroll
        for (int m = 0; m < KW; ++m) s += wp[m];
        tmpw[t] = s;
    }
    __syncthreads();
    if (t < KW) {
        float s = 0.f;
        #pragma unroll
        for (int j = 0; j < KW; ++j) s += tmpw[t * KW + j];
        w1s[t] = s;
    }
    __syncthreads();
    float w1r[KW];
    #pragma unroll
    for (int k = 0; k < KW; ++k) w1r[k] = w1s[k];

    // ---- staging task decode (1 or 2 float4 tasks per thread) ----
    const int ntask = (t < NTASK - 256) ? 2 : 1;   // t<108 -> 2 tasks
    const float* s_ptr[2];   // global base (incl. n, h, w offsets), + z*HSZ later
    int  s_lds[2];           // float offset into rawf
    bool s_in[2];
    {
        const long ibase = (long)n * DI * HSZ;
        #pragma unroll
        for (int q = 0; q < 2; ++q) {
            const int u = t + 256 * q;
            const int im = (u >= RR * 7) ? 1 : 0;
            const int pos = u - im * (RR * 7);
            const int r = pos / 7, c4 = pos - r * 7;
            const int gh = h0 + r, gw0 = w0 + 4 * c4;
            s_in[q]  = (gh < HI) && (gw0 < WI);   // all-or-nothing per float4
            s_lds[q] = im * (RR * RST) + r * RST + 4 * c4;
            s_ptr[q] = (im ? img2 : img1) + ibase + (long)gh * WI + gw0;
        }
    }
    #define LOADQ(q, z) (s_in[q] ? *(const float4*)(s_ptr[q] + (long)(z) * HSZ) \
                                 : make_float4(0.f, 0.f, 0.f, 0.f))

    // D-conv ring accumulators: 4 fields (a, b, ab, a^2+b^2).
    float rA[KW], rB[KW], rP[KW], rQ[KW];
    #pragma unroll
    for (int p = 0; p < KW; ++p) { rA[p]=0.f; rB[p]=0.f; rP[p]=0.f; rQ[p]=0.f; }

    const int ty = t >> 4, tx = t & 15;
    const bool valid = (h0 + ty < HOUT) && (w0 + tx < WOUT);
    float partial = 0.f;

    // ---- prologue: stage slice 0, prefetch slice 1 ----
    float4 pf0, pf1;
    pf0 = LOADQ(0, d0);
    if (ntask == 2) pf1 = LOADQ(1, d0);
    *(float4*)&rawf[s_lds[0]] = pf0;
    if (ntask == 2) *(float4*)&rawf[s_lds[1]] = pf1;
    pf0 = LOADQ(0, d0 + 1);
    if (ntask == 2) pf1 = LOADQ(1, d0 + 1);
    __syncthreads();

    int jj = 0;   // zz % 11 (uniform scalar)
    for (int zz = 0; zz < ZSL; ++zz) {
        // ---- phase A: W-conv of 4 fields, 208 threads x 2 outputs ----
        if (t < RR * 8) {
            const int r = t >> 3, c0 = (t & 7) * 2;
            const float* r0 = &rawf[r * RST + c0];
            const float* r1 = r0 + RR * RST;
            float xa[12], xb[12];
            #pragma unroll
            for (int m = 0; m < 6; ++m) {
                const float2 va = *(const float2*)(r0 + 2 * m);
                const float2 vb = *(const float2*)(r1 + 2 * m);
                xa[2*m] = va.x; xa[2*m+1] = va.y;
                xb[2*m] = vb.x; xb[2*m+1] = vb.y;
            }
            float s1[2] = {0.f, 0.f}, s2[2] = {0.f, 0.f};
            float s3[2] = {0.f, 0.f}, s4[2] = {0.f, 0.f};
            #pragma unroll
            for (int k = 0; k < KW; ++k) {
                const float wk = w1r[k];
                #pragma unroll
                for (int o = 0; o < 2; ++o) {
                    const float x = xa[o + k], y = xb[o + k];
                    s1[o] = fmaf(wk, x, s1[o]);
                    s2[o] = fmaf(wk, y, s2[o]);
                    s3[o] = fmaf(wk, x * y, s3[o]);
                    s4[o] = fmaf(wk, fmaf(x, x, y * y), s4[o]);
                }
            }
            #pragma unroll
            for (int o = 0; o < 2; ++o)
                A4[r][c0 + o] = make_float4(s1[o], s2[o], s3[o], s4[o]);
        }
        __syncthreads();

        // ---- phase B: H-conv + D-ring + emit; stage z+1; prefetch z+2 ----
        float f1 = 0.f, f2 = 0.f, f3 = 0.f, f4 = 0.f;
        #pragma unroll
        for (int kh = 0; kh < KW; ++kh) {
            const float w = w1r[kh];
            const float4 v = A4[ty + kh][tx];
            f1 = fmaf(w, v.x, f1);
            f2 = fmaf(w, v.y, f2);
            f3 = fmaf(w, v.z, f3);
            f4 = fmaf(w, v.w, f4);
        }

        if (zz + 1 < ZSL) {   // write prefetched slice z+1 into raw
            *(float4*)&rawf[s_lds[0]] = pf0;
            if (ntask == 2) *(float4*)&rawf[s_lds[1]] = pf1;
        }
        if (zz + 2 < ZSL) {   // issue loads for slice z+2 (in flight ~1 full iter)
            pf0 = LOADQ(0, d0 + zz + 2);
            if (ntask == 2) pf1 = LOADQ(1, d0 + zz + 2);
        }

        const bool emit = (zz >= KW - 1);
        float o1, o2, o3, o4;
        switch (jj) {
            case 0:  acc_step<0>(rA,rB,rP,rQ,w1r,f1,f2,f3,f4,emit,o1,o2,o3,o4); break;
            case 1:  acc_step<1>(rA,rB,rP,rQ,w1r,f1,f2,f3,f4,emit,o1,o2,o3,o4); break;
            case 2:  acc_step<2>(rA,rB,rP,rQ,w1r,f1,f2,f3,f4,emit,o1,o2,o3,o4); break;
            case 3:  acc_step<3>(rA,rB,rP,rQ,w1r,f1,f2,f3,f4,emit,o1,o2,o3,o4); break;
            case 4:  acc_step<4>(rA,rB,rP,rQ,w1r,f1,f2,f3,f4,emit,o1,o2,o3,o4); break;
            case 5:  acc_step<5>(rA,rB,rP,rQ,w1r,f1,f2,f3,f4,emit,o1,o2,o3,o4); break;
            case 6:  acc_step<6>(rA,rB,rP,rQ,w1r,f1,f2,f3,f4,emit,o1,o2,o3,o4); break;
            case 7:  acc_step<7>(rA,rB,rP,rQ,w1r,f1,f2,f3,f4,emit,o1,o2,o3,o4); break;
            case 8:  acc_step<8>(rA,rB,rP,rQ,w1r,f1,f2,f3,f4,emit,o1,o2,o3,o4); break;
            case 9:  acc_step<9>(rA,rB,rP,rQ,w1r,f1,f2,f3,f4,emit,o1,o2,o3,o4); break;
            default: acc_step<10>(rA,rB,rP,rQ,w1r,f1,f2,f3,f4,emit,o1,o2,o3,o4); break;
        }
        jj = (jj == KW - 1) ? 0 : jj + 1;

        if (emit && valid) {
            const float mu1 = o1, mu2 = o2;
            const float m11 = mu1 * mu1, m22 = mu2 * mu2, m12 = mu1 * mu2;
            const float num = (2.f * m12 + SSIM_C1) * (2.f * (o3 - m12) + SSIM_C2);
            const float den = (m11 + m22 + SSIM_C1) * ((o4 - m11 - m22) + SSIM_C2);
            partial += num / den;
        }
        __syncthreads();
    }

    // ---- block reduction -> per-block partial sum ----
    #pragma unroll
    for (int off = 32; off >= 1; off >>= 1)
        partial += __shfl_down(partial, off, 64);
    if ((t & 63) == 0) red[t >> 6] = partial;
    __syncthreads();
    if (t == 0) {
        bsum[(blockIdx.z * gridDim.y + blockIdx.y) * gridDim.x + blockIdx.x]
            = red[0] + red[1] + red[2] + red[3];
    }
}

static __global__ __launch_bounds__(256) void ssim_reduce(
    const float* __restrict__ bsum, float* __restrict__ out)
{
    __shared__ double red[4];
    const int t = threadIdx.x;
    double s = 0.0;
    for (int i = t; i < NBLK; i += 256) s += (double)bsum[i];
    #pragma unroll
    for (int off = 32; off >= 1; off >>= 1)
        s += __shfl_down(s, off, 64);
    if ((t & 63) == 0) red[t >> 6] = s;
    __syncthreads();
    if (t == 0) {
        const double tot = red[0] + red[1] + red[2] + red[3];
        out[0] = (float)(tot / (double)((long)NB * DOUT * HOUT * WOUT));
    }
}

extern "C" void kernel_launch(void* const* d_in, const int* in_sizes, int n_in,
                              void* d_out, int out_size, void* d_ws, size_t ws_size,
                              hipStream_t stream)
{
    const float* img1 = (const float*)d_in[0];
    const float* img2 = (const float*)d_in[1];
    const float* win  = (const float*)d_in[2];
    float* out  = (float*)d_out;
    float* bsum = (float*)d_ws;   // 2048 floats = 8 KB scratch

    dim3 grid(TW, TH, NB * DCH);
    ssim_main<<<grid, 256, 0, stream>>>(img1, img2, win, bsum);
    ssim_reduce<<<1, 256, 0, stream>>>(bsum, out);
}